// Round 9
// baseline (308.235 us; speedup 1.0000x reference)
//
#include <hip/hip_runtime.h>
#include <cstdint>

#define DIMC 2048
#define NSEQ 2048
#define BATCH 2
#define NH 16
#define HD 128
#define MROWS 4096            // BATCH*NSEQ
#define NQKV 6144             // 3*DIMC
#define QSCALE 0.08838834764831845f

typedef float f32x4 __attribute__((ext_vector_type(4)));
typedef __bf16 bf16x8 __attribute__((ext_vector_type(8)));
typedef __bf16 bf16x4 __attribute__((ext_vector_type(4)));

__device__ __forceinline__ f32x4 mfma16(bf16x8 a, bf16x8 b, f32x4 c) {
  return __builtin_amdgcn_mfma_f32_16x16x32_bf16(a, b, c, 0, 0, 0);
}

typedef __attribute__((address_space(1))) void gvoid;
typedef __attribute__((address_space(3))) void ldsvoid;

__device__ __forceinline__ void async16(void* lds, const void* g) {
  __builtin_amdgcn_global_load_lds((gvoid*)(uintptr_t)g, (ldsvoid*)(uintptr_t)lds, 16, 0, 0);
}

#define BAR() asm volatile("s_barrier" ::: "memory")
#define VMCNT0() asm volatile("s_waitcnt vmcnt(0)" ::: "memory")

// ---------------------------------------------------------------------------
// fp32 -> bf16 casts
// ---------------------------------------------------------------------------
__global__ __launch_bounds__(256) void cast_x(const float* __restrict__ src,
                                              __bf16* __restrict__ dst) {
  const int i = (blockIdx.x * 256 + threadIdx.x) * 4;
  const float4 v = *(const float4*)(src + i);
  bf16x4 o = {(__bf16)v.x, (__bf16)v.y, (__bf16)v.z, (__bf16)v.w};
  *(bf16x4*)(dst + i) = o;
}

__global__ __launch_bounds__(256) void cast_w(const float* __restrict__ Wq,
                                              const float* __restrict__ Wk,
                                              const float* __restrict__ Wv,
                                              const float* __restrict__ Wo,
                                              __bf16* __restrict__ Wqkvb,
                                              __bf16* __restrict__ Wob) {
  const int m = blockIdx.y;
  const float* s = (m == 0) ? Wq : (m == 1) ? Wk : (m == 2) ? Wv : Wo;
  __bf16* d = (m == 3) ? Wob : Wqkvb + (size_t)m * DIMC * DIMC;
  const int i = (blockIdx.x * 256 + threadIdx.x) * 4;
  const float4 v = *(const float4*)(s + i);
  bf16x4 o = {(__bf16)v.x, (__bf16)v.y, (__bf16)v.z, (__bf16)v.w};
  *(bf16x4*)(d + i) = o;
}

// ---------------------------------------------------------------------------
// GEMM  C[M][N] = A[M][K] * B[N][K]^T (+bias), K = 2048, 128x128 tile (m97).
// EPI 0: QKV epilogue; EPI 1: out epilogue (fp32 to d_out).
// ---------------------------------------------------------------------------
template <int EPI>
__global__ __launch_bounds__(256) void gemm_bt(
    const __bf16* __restrict__ A, const __bf16* __restrict__ Bm,
    __bf16* __restrict__ Qb, __bf16* __restrict__ Kb, __bf16* __restrict__ Vtb,
    const float* __restrict__ bias0, const float* __restrict__ bias1,
    const float* __restrict__ bias2, float* __restrict__ outp) {
  __shared__ __bf16 Al[128 * 32];
  __shared__ __bf16 Bl[128 * 32];
  const int tid = threadIdx.x;
  const int w = tid >> 6, l = tid & 63;
  const int a = l & 15, g = l >> 4;
  const int mbase = blockIdx.y * 128, nbase = blockIdx.x * 128;
  const int wr = w >> 1, wc = w & 1;

  f32x4 acc[4][4] = {};

  const char* Ag = (const char*)A +
      ((size_t)(mbase + w * 32 + (l >> 2)) * DIMC + (size_t)(l & 3) * 8) * 2;
  const char* Bg = (const char*)Bm +
      ((size_t)(nbase + w * 32 + (l >> 2)) * DIMC + (size_t)(l & 3) * 8) * 2;
  char* Alw = (char*)Al + w * 2048;
  char* Blw = (char*)Bl + w * 2048;

  for (int kt = 0; kt < DIMC / 32; ++kt) {
    const size_t ko = (size_t)kt * 64;
    async16(Alw, Ag + ko);
    async16(Alw + 1024, Ag + (size_t)16 * (DIMC * 2) + ko);
    async16(Blw, Bg + ko);
    async16(Blw + 1024, Bg + (size_t)16 * (DIMC * 2) + ko);
    __syncthreads();
    bf16x8 af[4], bf_[4];
#pragma unroll
    for (int m = 0; m < 4; ++m)
      af[m] = *(const bf16x8*)((const char*)Al + (wr * 64 + m * 16 + a) * 64 + g * 16);
#pragma unroll
    for (int n = 0; n < 4; ++n)
      bf_[n] = *(const bf16x8*)((const char*)Bl + (wc * 64 + n * 16 + a) * 64 + g * 16);
#pragma unroll
    for (int m = 0; m < 4; ++m)
#pragma unroll
      for (int n = 0; n < 4; ++n) acc[m][n] = mfma16(af[m], bf_[n], acc[m][n]);
    __syncthreads();
  }

  if constexpr (EPI == 0) {
    const int seg = nbase >> 11;               // 0=q 1=k 2=v
    const int cin = (nbase & 2047) + wc * 64;
    const float* bias = (seg == 0) ? bias0 : ((seg == 1) ? bias1 : bias2);
    const float scl = (seg == 0) ? QSCALE : 1.0f;
#pragma unroll
    for (int n = 0; n < 4; ++n) {
      const int c = cin + n * 16 + a;
      const float bb = bias[c];
      const int h = c >> 7, d = c & 127;
#pragma unroll
      for (int m = 0; m < 4; ++m) {
        const int mr = mbase + wr * 64 + m * 16 + g * 4;
        const int b_ = mr >> 11, sq = mr & 2047;
        f32x4 v = acc[m][n];
        if (seg == 2) {
          __bf16* dst = Vtb + ((size_t)(b_ * NH + h) * HD + d) * NSEQ + sq;
          bf16x4 pk = {(__bf16)(v[0] + bb), (__bf16)(v[1] + bb),
                       (__bf16)(v[2] + bb), (__bf16)(v[3] + bb)};
          *(bf16x4*)dst = pk;
        } else {
          __bf16* dst = ((seg == 0) ? Qb : Kb) +
                        ((size_t)(b_ * NH + h) * NSEQ + sq) * HD + d;
#pragma unroll
          for (int j = 0; j < 4; ++j) dst[(size_t)j * HD] = (__bf16)((v[j] + bb) * scl);
        }
      }
    }
  } else {
#pragma unroll
    for (int n = 0; n < 4; ++n) {
      const int c = nbase + wc * 64 + n * 16 + a;
      const float bb = bias0[c];
#pragma unroll
      for (int m = 0; m < 4; ++m) {
        const int mr = mbase + wr * 64 + m * 16 + g * 4;
        float* dst = outp + (size_t)mr * DIMC + c;
        f32x4 v = acc[m][n];
#pragma unroll
        for (int j = 0; j < 4; ++j) dst[(size_t)j * DIMC] = v[j] + bb;
      }
    }
  }
}

// ---------------------------------------------------------------------------
// Sliding-window flash attention v5: 4 waves x 64 q (was 8 x 32).
// LDS-BW model: per-CU per-tile LDS bytes = W x (K 16KB + V 16KB) + P;
// halving W at fixed QBLK=256 halves the dominant K/V fragment re-reads
// (320KB -> 192KB per tile). VGPR grows to ~300 (qf 64 + o 128 + s4 64) --
// measured-safe (no spill through 450, m08/m24); 1 wave/SIMD is fine since
// the LDS pipe is CU-shared. Swapped-operand S^T/O^T structure retained.
// ---------------------------------------------------------------------------
__global__ __launch_bounds__(256, 1) void attn_swa5(const __bf16* __restrict__ Qb,
                                                    const __bf16* __restrict__ Kb,
                                                    const __bf16* __restrict__ Vtb,
                                                    __bf16* __restrict__ Ob) {
  extern __shared__ __align__(16) char AL[];
  const int tid = threadIdx.x;
  const int w = tid >> 6, l = tid & 63;
  const int a = l & 15, g = l >> 4;
  const int bh = blockIdx.y;
  const int qbase = blockIdx.x * 256;
  const __bf16* Qg = Qb + (size_t)bh * NSEQ * HD;
  const char* Kg = (const char*)(Kb + (size_t)bh * NSEQ * HD);
  const char* Vg = (const char*)(Vtb + (size_t)bh * HD * NSEQ);

  // Q fragments: 4 qi x 4 d-slices; this wave owns q rows w*64 .. w*64+63
  bf16x8 qf[4][4];
#pragma unroll
  for (int qi = 0; qi < 4; ++qi)
#pragma unroll
    for (int s = 0; s < 4; ++s)
      qf[qi][s] = *(const bf16x8*)(Qg + (size_t)(qbase + w * 64 + qi * 16 + a) * HD + s * 32 + g * 8);

  float mrow[4] = {-1e38f, -1e38f, -1e38f, -1e38f};
  float lrow[4] = {0.f, 0.f, 0.f, 0.f};
  f32x4 o[4][8] = {};   // O^T: o[qi][n][reg] = O[d = n*16+g*4+reg][q = qi*16+a]

  const int ktlo = (qbase >= 1024) ? ((qbase - 1024) >> 6) : 0;
  const int kthi = (qbase + 255) >> 6;

  // 256 threads stage one 32KB tile-pair: K [64 kv][128 d] + Vt [128 d][64 kv],
  // 4 x 4KB lines each; chunk-XOR (row&7) pre-swizzled on the global source.
  auto stage = [&](int b, int kt) {
    const int kb2 = kt * 64;
    char* Kl = AL + b * 32768;
    char* Vl = AL + b * 32768 + 16384;
#pragma unroll
    for (int j = 0; j < 4; ++j) {
      const int row = j * 16 + (tid >> 4);
      const int ch = (tid & 15) ^ ((tid >> 4) & 7);
      async16(Kl + j * 4096 + w * 1024, Kg + (size_t)(kb2 + row) * 256 + ch * 16);
    }
#pragma unroll
    for (int j = 0; j < 4; ++j) {
      const int row = j * 32 + (tid >> 3);
      const int ch = (tid & 7) ^ ((tid >> 3) & 7);
      async16(Vl + j * 4096 + w * 1024,
              Vg + (size_t)row * (NSEQ * 2) + (size_t)kb2 * 2 + ch * 16);
    }
  };

  stage(0, ktlo);
  VMCNT0(); BAR();
  int buf = 0;
  char* Pw = AL + 65536 + w * 8192;   // per-wave P[64 q][64 kv] bf16, swizzled

  for (int kt = ktlo; kt <= kthi; ++kt) {
    if (kt < kthi) stage(buf ^ 1, kt + 1);
    const char* Kl = AL + buf * 32768;
    const char* Vl = AL + buf * 32768 + 16384;
    const int kb2 = kt * 64;
    const bool full = (kb2 >= qbase + 255 - 1024) && (kb2 + 63 <= qbase);

    // S^T = K x Q^T : s4[qi][t][i] = S[kv = kb2+t*16+g*4+i][q = qi*16+a]
    f32x4 s4[4][4];
#pragma unroll
    for (int t = 0; t < 4; ++t) {
      bf16x8 kf[4];
#pragma unroll
      for (int ds = 0; ds < 4; ++ds)
        kf[ds] = *(const bf16x8*)(Kl + (t * 16 + a) * 256 + (((ds * 4 + g) ^ (a & 7)) * 16));
      __builtin_amdgcn_s_setprio(1);
#pragma unroll
      for (int qi = 0; qi < 4; ++qi) {
        f32x4 sc = {};
#pragma unroll
        for (int ds = 0; ds < 4; ++ds) sc = mfma16(kf[ds], qf[qi][ds], sc);
        s4[qi][t] = sc;
      }
      __builtin_amdgcn_s_setprio(0);
    }

    if (!full) {
#pragma unroll
      for (int qi = 0; qi < 4; ++qi) {
        const int q = qbase + w * 64 + qi * 16 + a;
#pragma unroll
        for (int t = 0; t < 4; ++t)
#pragma unroll
          for (int i = 0; i < 4; ++i) {
            const int kv = kb2 + t * 16 + g * 4 + i;
            if (kv > q || kv + 1024 < q) s4[qi][t][i] = -1e30f;
          }
      }
    }

#pragma unroll
    for (int qi = 0; qi < 4; ++qi) {
      float pm = s4[qi][0][0];
#pragma unroll
      for (int t = 0; t < 4; ++t)
#pragma unroll
        for (int i = 0; i < 4; ++i)
          if (t || i) pm = fmaxf(pm, s4[qi][t][i]);
      pm = fmaxf(pm, __shfl_xor(pm, 16));
      pm = fmaxf(pm, __shfl_xor(pm, 32));
      if (!__all(pm - mrow[qi] <= 8.f)) {   // T13 defer-max
        const float nm = fmaxf(mrow[qi], pm);
        const float corr = __expf(mrow[qi] - nm);
        mrow[qi] = nm;
        lrow[qi] *= corr;
#pragma unroll
        for (int n = 0; n < 8; ++n)
#pragma unroll
          for (int i = 0; i < 4; ++i) o[qi][n][i] *= corr;
      }
      float rs = 0.f;
#pragma unroll
      for (int t = 0; t < 4; ++t)
#pragma unroll
        for (int i = 0; i < 4; ++i) {
          const float p = __expf(s4[qi][t][i] - mrow[qi]);
          s4[qi][t][i] = p;
          rs += p;
        }
      rs += __shfl_xor(rs, 16);
      rs += __shfl_xor(rs, 32);
      lrow[qi] += rs;
      // P[q][kv] -> per-wave LDS: 4 packed 8B stores; XOR hits bits 4-6 only.
      const int prow = qi * 16 + a;
#pragma unroll
      for (int t = 0; t < 4; ++t) {
        bf16x4 pk = {(__bf16)s4[qi][t][0], (__bf16)s4[qi][t][1],
                     (__bf16)s4[qi][t][2], (__bf16)s4[qi][t][3]};
        const int byte = (prow * 128 + (t * 16 + g * 4) * 2) ^ ((a & 7) << 4);
        *(bf16x4*)(Pw + byte) = pk;
      }
    }

    // O^T += V^T x P^T (A = Vt frag, B = P frag; V read once per (ks,n))
#pragma unroll
    for (int ks = 0; ks < 2; ++ks) {
      bf16x8 pa[4];
#pragma unroll
      for (int qi = 0; qi < 4; ++qi)
        pa[qi] = *(const bf16x8*)(Pw + (((qi * 16 + a) * 128 + ks * 64 + g * 16) ^ ((a & 7) << 4)));
#pragma unroll
      for (int n = 0; n < 8; ++n) {
        bf16x8 va = *(const bf16x8*)(Vl + (n * 16 + a) * 128 + (((ks * 4 + g) ^ (a & 7)) * 16));
        __builtin_amdgcn_s_setprio(1);
#pragma unroll
        for (int qi = 0; qi < 4; ++qi) o[qi][n] = mfma16(va, pa[qi], o[qi][n]);
        __builtin_amdgcn_s_setprio(0);
      }
    }

    VMCNT0(); BAR();
    buf ^= 1;
  }

  const int b_ = bh >> 4, h = bh & 15;
#pragma unroll
  for (int qi = 0; qi < 4; ++qi) {
    const int q = qbase + w * 64 + qi * 16 + a;
    const float inv = 1.f / lrow[qi];
    __bf16* Og = Ob + (size_t)(b_ * NSEQ + q) * DIMC + h * HD + g * 4;
#pragma unroll
    for (int n = 0; n < 8; ++n) {
      bf16x4 pk = {(__bf16)(o[qi][n][0] * inv), (__bf16)(o[qi][n][1] * inv),
                   (__bf16)(o[qi][n][2] * inv), (__bf16)(o[qi][n][3] * inv)};
      *(bf16x4*)(Og + (size_t)n * 16) = pk;
    }
  }
}

// ---------------------------------------------------------------------------
extern "C" void kernel_launch(void* const* d_in, const int* in_sizes, int n_in,
                              void* d_out, int out_size, void* d_ws, size_t ws_size,
                              hipStream_t stream) {
  const float* x = (const float*)d_in[0];
  const float* Wq = (const float*)d_in[1];
  const float* bq = (const float*)d_in[2];
  const float* Wk = (const float*)d_in[3];
  const float* bk = (const float*)d_in[4];
  const float* Wv = (const float*)d_in[5];
  const float* bv = (const float*)d_in[6];
  const float* Wo = (const float*)d_in[7];
  const float* bo = (const float*)d_in[8];
  float* out = (float*)d_out;

  char* ws = (char*)d_ws;
  __bf16* xb    = (__bf16*)(ws + 0);          // 16.78 MB (reused as Ob)
  __bf16* Wqkvb = (__bf16*)(ws + 16777216);   // 25.17 MB
  __bf16* Wob   = (__bf16*)(ws + 41943040);   // 8.39 MB
  __bf16* Qb    = (__bf16*)(ws + 50331648);   // 16.78 MB
  __bf16* Kb    = (__bf16*)(ws + 67108864);   // 16.78 MB
  __bf16* Vtb   = (__bf16*)(ws + 83886080);   // 16.78 MB -> total 100.66 MB
  __bf16* Ob    = xb;

  (void)hipFuncSetAttribute((const void*)attn_swa5,
                            hipFuncAttributeMaxDynamicSharedMemorySize, 98304);

  cast_x<<<dim3(MROWS * DIMC / 1024), 256, 0, stream>>>(x, xb);
  cast_w<<<dim3(DIMC * DIMC / 1024, 4), 256, 0, stream>>>(Wq, Wk, Wv, Wo, Wqkvb, Wob);

  gemm_bt<0><<<dim3(NQKV / 128, MROWS / 128), 256, 0, stream>>>(
      xb, Wqkvb, Qb, Kb, Vtb, bq, bk, bv, nullptr);

  attn_swa5<<<dim3(NSEQ / 256, BATCH * NH), 256, 98304, stream>>>(Qb, Kb, Vtb, Ob);

  gemm_bt<1><<<dim3(DIMC / 128, MROWS / 128), 256, 0, stream>>>(
      Ob, Wob, nullptr, nullptr, nullptr, bo, nullptr, nullptr, out);
}

// Round 10
// 250.117 us; speedup vs baseline: 1.2324x; 1.2324x over previous
//
#include <hip/hip_runtime.h>
#include <cstdint>

#define DIMC 2048
#define NSEQ 2048
#define BATCH 2
#define NH 16
#define HD 128
#define MROWS 4096            // BATCH*NSEQ
#define NQKV 6144             // 3*DIMC
#define QSCALE 0.08838834764831845f

typedef float f32x4 __attribute__((ext_vector_type(4)));
typedef __bf16 bf16x8 __attribute__((ext_vector_type(8)));
typedef __bf16 bf16x4 __attribute__((ext_vector_type(4)));

__device__ __forceinline__ f32x4 mfma16(bf16x8 a, bf16x8 b, f32x4 c) {
  return __builtin_amdgcn_mfma_f32_16x16x32_bf16(a, b, c, 0, 0, 0);
}

typedef __attribute__((address_space(1))) void gvoid;
typedef __attribute__((address_space(3))) void ldsvoid;

__device__ __forceinline__ void async16(void* lds, const void* g) {
  __builtin_amdgcn_global_load_lds((gvoid*)(uintptr_t)g, (ldsvoid*)(uintptr_t)lds, 16, 0, 0);
}

#define BAR() asm volatile("s_barrier" ::: "memory")
#define VMCNT0() asm volatile("s_waitcnt vmcnt(0)" ::: "memory")

// ---------------------------------------------------------------------------
// fused fp32 -> bf16 cast: x (8M elems) then Wq|Wk|Wv (as one 12M-elem run
// into Wqkvb) then Wo (4M into Wob). 24576 blocks x 256 thr x 4 elems.
// ---------------------------------------------------------------------------
__global__ __launch_bounds__(256) void cast_all(const float* __restrict__ x,
                                                const float* __restrict__ Wq,
                                                const float* __restrict__ Wk,
                                                const float* __restrict__ Wv,
                                                const float* __restrict__ Wo,
                                                __bf16* __restrict__ xb,
                                                __bf16* __restrict__ Wqkvb,
                                                __bf16* __restrict__ Wob) {
  const int i = (blockIdx.x * 256 + threadIdx.x) * 4;
  const int WN = DIMC * DIMC;             // 4M
  const float* s;
  __bf16* d;
  if (i < MROWS * DIMC) { s = x + i; d = xb + i; }
  else {
    const int j = i - MROWS * DIMC;
    const int m = j / WN, r = j - m * WN;
    s = ((m == 0) ? Wq : (m == 1) ? Wk : (m == 2) ? Wv : Wo) + r;
    d = ((m == 3) ? Wob : Wqkvb + (size_t)m * WN) + r;
  }
  const float4 v = *(const float4*)s;
  bf16x4 o = {(__bf16)v.x, (__bf16)v.y, (__bf16)v.z, (__bf16)v.w};
  *(bf16x4*)d = o;
}

// ---------------------------------------------------------------------------
// GEMM  C[M][N] = A[M][K] * B[N][K]^T (+bias), K = 2048, 128x128 tile (m97).
// EPI 0: QKV epilogue; EPI 1: out epilogue (fp32 to d_out).
// ---------------------------------------------------------------------------
template <int EPI>
__global__ __launch_bounds__(256) void gemm_bt(
    const __bf16* __restrict__ A, const __bf16* __restrict__ Bm,
    __bf16* __restrict__ Qb, __bf16* __restrict__ Kb, __bf16* __restrict__ Vtb,
    const float* __restrict__ bias0, const float* __restrict__ bias1,
    const float* __restrict__ bias2, float* __restrict__ outp) {
  __shared__ __bf16 Al[128 * 32];
  __shared__ __bf16 Bl[128 * 32];
  const int tid = threadIdx.x;
  const int w = tid >> 6, l = tid & 63;
  const int a = l & 15, g = l >> 4;
  const int mbase = blockIdx.y * 128, nbase = blockIdx.x * 128;
  const int wr = w >> 1, wc = w & 1;

  f32x4 acc[4][4] = {};

  const char* Ag = (const char*)A +
      ((size_t)(mbase + w * 32 + (l >> 2)) * DIMC + (size_t)(l & 3) * 8) * 2;
  const char* Bg = (const char*)Bm +
      ((size_t)(nbase + w * 32 + (l >> 2)) * DIMC + (size_t)(l & 3) * 8) * 2;
  char* Alw = (char*)Al + w * 2048;
  char* Blw = (char*)Bl + w * 2048;

  for (int kt = 0; kt < DIMC / 32; ++kt) {
    const size_t ko = (size_t)kt * 64;
    async16(Alw, Ag + ko);
    async16(Alw + 1024, Ag + (size_t)16 * (DIMC * 2) + ko);
    async16(Blw, Bg + ko);
    async16(Blw + 1024, Bg + (size_t)16 * (DIMC * 2) + ko);
    __syncthreads();
    bf16x8 af[4], bf_[4];
#pragma unroll
    for (int m = 0; m < 4; ++m)
      af[m] = *(const bf16x8*)((const char*)Al + (wr * 64 + m * 16 + a) * 64 + g * 16);
#pragma unroll
    for (int n = 0; n < 4; ++n)
      bf_[n] = *(const bf16x8*)((const char*)Bl + (wc * 64 + n * 16 + a) * 64 + g * 16);
#pragma unroll
    for (int m = 0; m < 4; ++m)
#pragma unroll
      for (int n = 0; n < 4; ++n) acc[m][n] = mfma16(af[m], bf_[n], acc[m][n]);
    __syncthreads();
  }

  if constexpr (EPI == 0) {
    const int seg = nbase >> 11;               // 0=q 1=k 2=v
    const int cin = (nbase & 2047) + wc * 64;
    const float* bias = (seg == 0) ? bias0 : ((seg == 1) ? bias1 : bias2);
    const float scl = (seg == 0) ? QSCALE : 1.0f;
#pragma unroll
    for (int n = 0; n < 4; ++n) {
      const int c = cin + n * 16 + a;
      const float bb = bias[c];
      const int h = c >> 7, d = c & 127;
#pragma unroll
      for (int m = 0; m < 4; ++m) {
        const int mr = mbase + wr * 64 + m * 16 + g * 4;
        const int b_ = mr >> 11, sq = mr & 2047;
        f32x4 v = acc[m][n];
        if (seg == 2) {
          __bf16* dst = Vtb + ((size_t)(b_ * NH + h) * HD + d) * NSEQ + sq;
          bf16x4 pk = {(__bf16)(v[0] + bb), (__bf16)(v[1] + bb),
                       (__bf16)(v[2] + bb), (__bf16)(v[3] + bb)};
          *(bf16x4*)dst = pk;
        } else {
          __bf16* dst = ((seg == 0) ? Qb : Kb) +
                        ((size_t)(b_ * NH + h) * NSEQ + sq) * HD + d;
#pragma unroll
          for (int j = 0; j < 4; ++j) dst[(size_t)j * HD] = (__bf16)((v[j] + bb) * scl);
        }
      }
    }
  } else {
#pragma unroll
    for (int n = 0; n < 4; ++n) {
      const int c = nbase + wc * 64 + n * 16 + a;
      const float bb = bias0[c];
#pragma unroll
      for (int m = 0; m < 4; ++m) {
        const int mr = mbase + wr * 64 + m * 16 + g * 4;
        float* dst = outp + (size_t)mr * DIMC + c;
        f32x4 v = acc[m][n];
#pragma unroll
        for (int j = 0; j < 4; ++j) dst[(size_t)j * DIMC] = v[j] + bb;
      }
    }
  }
}

// ---------------------------------------------------------------------------
// Sliding-window flash attention v6 = R8-validated v4 (8 waves x 32 q,
// swapped-operand S^T/O^T, packed P-writes, setprio, defer-max) + XCD
// head-grouping: 1-D grid of 256; id = (bh%8) + 8*qx + 64*(bh>>3) puts all
// 8 q-blocks of a head on one XCD (id%8 = const) -> that head's 1MB KV is
// L2-resident for the staging drain; 4 heads/XCD = 4MB = L2 size.
// ---------------------------------------------------------------------------
__global__ __launch_bounds__(512) void attn_swa6(const __bf16* __restrict__ Qb,
                                                 const __bf16* __restrict__ Kb,
                                                 const __bf16* __restrict__ Vtb,
                                                 __bf16* __restrict__ Ob) {
  extern __shared__ __align__(16) char AL[];
  const int tid = threadIdx.x;
  const int w = tid >> 6, l = tid & 63;
  const int a = l & 15, g = l >> 4;
  // XCD swizzle decode: bh = (id&7) + 8*(id>>6), qx = (id>>3)&7
  const int id = blockIdx.x;
  const int bh = (id & 7) + ((id >> 6) << 3);
  const int qbase = ((id >> 3) & 7) * 256;
  const __bf16* Qg = Qb + (size_t)bh * NSEQ * HD;
  const char* Kg = (const char*)(Kb + (size_t)bh * NSEQ * HD);
  const char* Vg = (const char*)(Vtb + (size_t)bh * HD * NSEQ);

  bf16x8 qf[2][4];
#pragma unroll
  for (int qi = 0; qi < 2; ++qi)
#pragma unroll
    for (int s = 0; s < 4; ++s)
      qf[qi][s] = *(const bf16x8*)(Qg + (size_t)(qbase + w * 32 + qi * 16 + a) * HD + s * 32 + g * 8);

  float mrow[2] = {-1e38f, -1e38f}, lrow[2] = {0.f, 0.f};
  f32x4 o[2][8] = {};   // O^T: o[qi][n][reg] = O[d = n*16+g*4+reg][q = qi*16+a]

  const int ktlo = (qbase >= 1024) ? ((qbase - 1024) >> 6) : 0;
  const int kthi = (qbase + 255) >> 6;

  auto stage = [&](int b, int kt) {
    const int kb2 = kt * 64;
    char* Kl = AL + b * 32768;
    char* Vl = AL + b * 32768 + 16384;
#pragma unroll
    for (int j = 0; j < 2; ++j) {  // K tile [64 kv][128 d]
      const int row = j * 32 + (tid >> 4);
      const int ch = (tid & 15) ^ ((tid >> 4) & 7);
      async16(Kl + j * 8192 + w * 1024, Kg + (size_t)(kb2 + row) * 256 + ch * 16);
    }
#pragma unroll
    for (int j = 0; j < 2; ++j) {  // Vt tile [128 d][64 kv]
      const int row = j * 64 + (tid >> 3);
      const int ch = (tid & 7) ^ ((tid >> 3) & 7);
      async16(Vl + j * 8192 + w * 1024,
              Vg + (size_t)row * (NSEQ * 2) + (size_t)kb2 * 2 + ch * 16);
    }
  };

  stage(0, ktlo);
  VMCNT0(); BAR();
  int buf = 0;
  char* Pw = AL + 65536 + w * 4096;   // per-wave P[32 q][64 kv] bf16, swizzled

  for (int kt = ktlo; kt <= kthi; ++kt) {
    if (kt < kthi) stage(buf ^ 1, kt + 1);
    const char* Kl = AL + buf * 32768;
    const char* Vl = AL + buf * 32768 + 16384;
    const int kb2 = kt * 64;
    const bool full = (kb2 >= qbase + 255 - 1024) && (kb2 + 63 <= qbase);

    // S^T = K x Q^T : s4[qi][t][i] = S[kv = kb2+t*16+g*4+i][q = qi*16+a]
    f32x4 s4[2][4];
#pragma unroll
    for (int t = 0; t < 4; ++t) {
      bf16x8 kf[4];
#pragma unroll
      for (int ds = 0; ds < 4; ++ds)
        kf[ds] = *(const bf16x8*)(Kl + (t * 16 + a) * 256 + (((ds * 4 + g) ^ (a & 7)) * 16));
      __builtin_amdgcn_s_setprio(1);
#pragma unroll
      for (int qi = 0; qi < 2; ++qi) {
        f32x4 sc = {};
#pragma unroll
        for (int ds = 0; ds < 4; ++ds) sc = mfma16(kf[ds], qf[qi][ds], sc);
        s4[qi][t] = sc;
      }
      __builtin_amdgcn_s_setprio(0);
    }

    if (!full) {
#pragma unroll
      for (int qi = 0; qi < 2; ++qi) {
        const int q = qbase + w * 32 + qi * 16 + a;
#pragma unroll
        for (int t = 0; t < 4; ++t)
#pragma unroll
          for (int i = 0; i < 4; ++i) {
            const int kv = kb2 + t * 16 + g * 4 + i;
            if (kv > q || kv + 1024 < q) s4[qi][t][i] = -1e30f;
          }
      }
    }

#pragma unroll
    for (int qi = 0; qi < 2; ++qi) {
      float pm = s4[qi][0][0];
#pragma unroll
      for (int t = 0; t < 4; ++t)
#pragma unroll
        for (int i = 0; i < 4; ++i)
          if (t || i) pm = fmaxf(pm, s4[qi][t][i]);
      pm = fmaxf(pm, __shfl_xor(pm, 16));
      pm = fmaxf(pm, __shfl_xor(pm, 32));
      if (!__all(pm - mrow[qi] <= 8.f)) {   // T13 defer-max
        const float nm = fmaxf(mrow[qi], pm);
        const float corr = __expf(mrow[qi] - nm);
        mrow[qi] = nm;
        lrow[qi] *= corr;
#pragma unroll
        for (int n = 0; n < 8; ++n)
#pragma unroll
          for (int i = 0; i < 4; ++i) o[qi][n][i] *= corr;
      }
      float rs = 0.f;
#pragma unroll
      for (int t = 0; t < 4; ++t)
#pragma unroll
        for (int i = 0; i < 4; ++i) {
          const float p = __expf(s4[qi][t][i] - mrow[qi]);
          s4[qi][t][i] = p;
          rs += p;
        }
      rs += __shfl_xor(rs, 16);
      rs += __shfl_xor(rs, 32);
      lrow[qi] += rs;
      // P[q][kv] -> per-wave LDS: 4 packed 8B stores; XOR hits bits 4-6 only.
      const int prow = qi * 16 + a;
#pragma unroll
      for (int t = 0; t < 4; ++t) {
        bf16x4 pk = {(__bf16)s4[qi][t][0], (__bf16)s4[qi][t][1],
                     (__bf16)s4[qi][t][2], (__bf16)s4[qi][t][3]};
        const int byte = (prow * 128 + (t * 16 + g * 4) * 2) ^ ((a & 7) << 4);
        *(bf16x4*)(Pw + byte) = pk;
      }
    }

    // O^T += V^T x P^T (A = Vt frag, B = P frag; V read once per (ks,n))
#pragma unroll
    for (int ks = 0; ks < 2; ++ks) {
      bf16x8 pa[2];
#pragma unroll
      for (int qi = 0; qi < 2; ++qi)
        pa[qi] = *(const bf16x8*)(Pw + (((qi * 16 + a) * 128 + ks * 64 + g * 16) ^ ((a & 7) << 4)));
#pragma unroll
      for (int n = 0; n < 8; ++n) {
        bf16x8 va = *(const bf16x8*)(Vl + (n * 16 + a) * 128 + (((ks * 4 + g) ^ (a & 7)) * 16));
        __builtin_amdgcn_s_setprio(1);
#pragma unroll
        for (int qi = 0; qi < 2; ++qi) o[qi][n] = mfma16(va, pa[qi], o[qi][n]);
        __builtin_amdgcn_s_setprio(0);
      }
    }

    VMCNT0(); BAR();
    buf ^= 1;
  }

  const int b_ = bh >> 4, h = bh & 15;
#pragma unroll
  for (int qi = 0; qi < 2; ++qi) {
    const int q = qbase + w * 32 + qi * 16 + a;
    const float inv = 1.f / lrow[qi];
    __bf16* Og = Ob + (size_t)(b_ * NSEQ + q) * DIMC + h * HD + g * 4;
#pragma unroll
    for (int n = 0; n < 8; ++n) {
      bf16x4 pk = {(__bf16)(o[qi][n][0] * inv), (__bf16)(o[qi][n][1] * inv),
                   (__bf16)(o[qi][n][2] * inv), (__bf16)(o[qi][n][3] * inv)};
      *(bf16x4*)(Og + (size_t)n * 16) = pk;
    }
  }
}

// ---------------------------------------------------------------------------
extern "C" void kernel_launch(void* const* d_in, const int* in_sizes, int n_in,
                              void* d_out, int out_size, void* d_ws, size_t ws_size,
                              hipStream_t stream) {
  const float* x = (const float*)d_in[0];
  const float* Wq = (const float*)d_in[1];
  const float* bq = (const float*)d_in[2];
  const float* Wk = (const float*)d_in[3];
  const float* bk = (const float*)d_in[4];
  const float* Wv = (const float*)d_in[5];
  const float* bv = (const float*)d_in[6];
  const float* Wo = (const float*)d_in[7];
  const float* bo = (const float*)d_in[8];
  float* out = (float*)d_out;

  char* ws = (char*)d_ws;
  __bf16* xb    = (__bf16*)(ws + 0);          // 16.78 MB (reused as Ob)
  __bf16* Wqkvb = (__bf16*)(ws + 16777216);   // 25.17 MB
  __bf16* Wob   = (__bf16*)(ws + 41943040);   // 8.39 MB
  __bf16* Qb    = (__bf16*)(ws + 50331648);   // 16.78 MB
  __bf16* Kb    = (__bf16*)(ws + 67108864);   // 16.78 MB
  __bf16* Vtb   = (__bf16*)(ws + 83886080);   // 16.78 MB -> total 100.66 MB
  __bf16* Ob    = xb;

  (void)hipFuncSetAttribute((const void*)attn_swa6,
                            hipFuncAttributeMaxDynamicSharedMemorySize, 98304);

  cast_all<<<dim3((MROWS * DIMC + 4 * DIMC * DIMC) / 1024), 256, 0, stream>>>(
      x, Wq, Wk, Wv, Wo, xb, Wqkvb, Wob);

  gemm_bt<0><<<dim3(NQKV / 128, MROWS / 128), 256, 0, stream>>>(
      xb, Wqkvb, Qb, Kb, Vtb, bq, bk, bv, nullptr);

  attn_swa6<<<dim3(256), 512, 98304, stream>>>(Qb, Kb, Vtb, Ob);

  gemm_bt<1><<<dim3(DIMC / 128, MROWS / 128), 256, 0, stream>>>(
      Ob, Wob, nullptr, nullptr, nullptr, bo, nullptr, nullptr, out);
}

// Round 12
// 243.486 us; speedup vs baseline: 1.2659x; 1.0272x over previous
//
#include <hip/hip_runtime.h>
#include <cstdint>

#define DIMC 2048
#define NSEQ 2048
#define BATCH 2
#define NH 16
#define HD 128
#define MROWS 4096            // BATCH*NSEQ
#define NQKV 6144             // 3*DIMC
#define QSCALE 0.08838834764831845f

typedef float f32x4 __attribute__((ext_vector_type(4)));
typedef __bf16 bf16x8 __attribute__((ext_vector_type(8)));
typedef __bf16 bf16x4 __attribute__((ext_vector_type(4)));

__device__ __forceinline__ f32x4 mfma16(bf16x8 a, bf16x8 b, f32x4 c) {
  return __builtin_amdgcn_mfma_f32_16x16x32_bf16(a, b, c, 0, 0, 0);
}

typedef __attribute__((address_space(1))) void gvoid;
typedef __attribute__((address_space(3))) void ldsvoid;

__device__ __forceinline__ void async16(void* lds, const void* g) {
  __builtin_amdgcn_global_load_lds((gvoid*)(uintptr_t)g, (ldsvoid*)(uintptr_t)lds, 16, 0, 0);
}

#define BAR() asm volatile("s_barrier" ::: "memory")
#define VMCNT0() asm volatile("s_waitcnt vmcnt(0)" ::: "memory")

// ---------------------------------------------------------------------------
// fused fp32 -> bf16 cast: x then Wq|Wk|Wv -> Wqkvb, Wo -> Wob.
// ---------------------------------------------------------------------------
__global__ __launch_bounds__(256) void cast_all(const float* __restrict__ x,
                                                const float* __restrict__ Wq,
                                                const float* __restrict__ Wk,
                                                const float* __restrict__ Wv,
                                                const float* __restrict__ Wo,
                                                __bf16* __restrict__ xb,
                                                __bf16* __restrict__ Wqkvb,
                                                __bf16* __restrict__ Wob) {
  const int i = (blockIdx.x * 256 + threadIdx.x) * 4;
  const int WN = DIMC * DIMC;             // 4M
  const float* s;
  __bf16* d;
  if (i < MROWS * DIMC) { s = x + i; d = xb + i; }
  else {
    const int j = i - MROWS * DIMC;
    const int m = j / WN, r = j - m * WN;
    s = ((m == 0) ? Wq : (m == 1) ? Wk : (m == 2) ? Wv : Wo) + r;
    d = ((m == 3) ? Wob : Wqkvb + (size_t)m * WN) + r;
  }
  const float4 v = *(const float4*)s;
  bf16x4 o = {(__bf16)v.x, (__bf16)v.y, (__bf16)v.z, (__bf16)v.w};
  *(bf16x4*)d = o;
}

// ---------------------------------------------------------------------------
// GEMM  C[M][N] = A[M][K] * B[N][K]^T (+bias), K = 2048, 128x128 tile.
// R11: BK=64 (halves the per-iter vmcnt(0)+barrier drain count vs BK=32;
// LDS 32KB -> still 5 blocks/CU) + chunk-XOR swizzle on LDS rows.
// LDS[row][c] holds G[row][c ^ (row&7)] (16B chunks, 128B rows); staged via
// linear global_load_lds dest + pre-swizzled global source (rule 21).
// EPI 0: QKV epilogue; EPI 1: out epilogue (fp32 to d_out).
// ---------------------------------------------------------------------------
template <int EPI>
__global__ __launch_bounds__(256) void gemm_bt(
    const __bf16* __restrict__ A, const __bf16* __restrict__ Bm,
    __bf16* __restrict__ Qb, __bf16* __restrict__ Kb, __bf16* __restrict__ Vtb,
    const float* __restrict__ bias0, const float* __restrict__ bias1,
    const float* __restrict__ bias2, float* __restrict__ outp) {
  __shared__ __bf16 Al[128 * 64];
  __shared__ __bf16 Bl[128 * 64];
  const int tid = threadIdx.x;
  const int w = tid >> 6, l = tid & 63;
  const int a = l & 15, g = l >> 4;
  const int mbase = blockIdx.y * 128, nbase = blockIdx.x * 128;
  const int wr = w >> 1, wc = w & 1;

  f32x4 acc[4][4] = {};

  // staging: 16 ops x 1KB per matrix; op o covers rows o*8..o*8+7 (128B each).
  // lane -> row o*8 + (l>>3), source chunk (l&7)^(l>>3&7) (involution).
  const int rlane = l >> 3;
  const int chunk = ((l & 7) ^ rlane) * 16;
  const char* Ag = (const char*)A + (size_t)(mbase + rlane) * (DIMC * 2) + chunk;
  const char* Bg = (const char*)Bm + (size_t)(nbase + rlane) * (DIMC * 2) + chunk;

  for (int kt = 0; kt < DIMC / 64; ++kt) {   // 32 iters
    const size_t ko = (size_t)kt * 128;
#pragma unroll
    for (int j = 0; j < 4; ++j) {
      const int o = w * 4 + j;
      const size_t roff = (size_t)o * 8 * (DIMC * 2) + ko;
      async16((char*)Al + o * 1024, Ag + roff);
      async16((char*)Bl + o * 1024, Bg + roff);
    }
    __syncthreads();   // compiler drains vmcnt(0) before s_barrier
#pragma unroll
    for (int ks = 0; ks < 2; ++ks) {
      bf16x8 af[4], bf_[4];
      const int cxe = ((ks * 4 + g) ^ (a & 7)) * 16;   // swizzled chunk (row&7 = a&7)
#pragma unroll
      for (int m = 0; m < 4; ++m)
        af[m] = *(const bf16x8*)((const char*)Al + (wr * 64 + m * 16 + a) * 128 + cxe);
#pragma unroll
      for (int n = 0; n < 4; ++n)
        bf_[n] = *(const bf16x8*)((const char*)Bl + (wc * 64 + n * 16 + a) * 128 + cxe);
#pragma unroll
      for (int m = 0; m < 4; ++m)
#pragma unroll
        for (int n = 0; n < 4; ++n) acc[m][n] = mfma16(af[m], bf_[n], acc[m][n]);
    }
    __syncthreads();
  }

  if constexpr (EPI == 0) {
    const int seg = nbase >> 11;               // 0=q 1=k 2=v
    const int cin = (nbase & 2047) + wc * 64;
    const float* bias = (seg == 0) ? bias0 : ((seg == 1) ? bias1 : bias2);
    const float scl = (seg == 0) ? QSCALE : 1.0f;
#pragma unroll
    for (int n = 0; n < 4; ++n) {
      const int c = cin + n * 16 + a;
      const float bb = bias[c];
      const int h = c >> 7, d = c & 127;
#pragma unroll
      for (int m = 0; m < 4; ++m) {
        const int mr = mbase + wr * 64 + m * 16 + g * 4;
        const int b_ = mr >> 11, sq = mr & 2047;
        f32x4 v = acc[m][n];
        if (seg == 2) {
          __bf16* dst = Vtb + ((size_t)(b_ * NH + h) * HD + d) * NSEQ + sq;
          bf16x4 pk = {(__bf16)(v[0] + bb), (__bf16)(v[1] + bb),
                       (__bf16)(v[2] + bb), (__bf16)(v[3] + bb)};
          *(bf16x4*)dst = pk;
        } else {
          __bf16* dst = ((seg == 0) ? Qb : Kb) +
                        ((size_t)(b_ * NH + h) * NSEQ + sq) * HD + d;
#pragma unroll
          for (int j = 0; j < 4; ++j) dst[(size_t)j * HD] = (__bf16)((v[j] + bb) * scl);
        }
      }
    }
  } else {
#pragma unroll
    for (int n = 0; n < 4; ++n) {
      const int c = nbase + wc * 64 + n * 16 + a;
      const float bb = bias0[c];
#pragma unroll
      for (int m = 0; m < 4; ++m) {
        const int mr = mbase + wr * 64 + m * 16 + g * 4;
        float* dst = outp + (size_t)mr * DIMC + c;
        f32x4 v = acc[m][n];
#pragma unroll
        for (int j = 0; j < 4; ++j) dst[(size_t)j * DIMC] = v[j] + bb;
      }
    }
  }
}

// ---------------------------------------------------------------------------
// Sliding-window flash attention v6 (unchanged from R10 win): 8 waves x 32 q,
// swapped-operand S^T/O^T, packed P-writes, setprio, defer-max, XCD
// head-grouping (id = (bh%8) + 8*qx + 64*(bh>>3)).
// ---------------------------------------------------------------------------
__global__ __launch_bounds__(512) void attn_swa6(const __bf16* __restrict__ Qb,
                                                 const __bf16* __restrict__ Kb,
                                                 const __bf16* __restrict__ Vtb,
                                                 __bf16* __restrict__ Ob) {
  extern __shared__ __align__(16) char AL[];
  const int tid = threadIdx.x;
  const int w = tid >> 6, l = tid & 63;
  const int a = l & 15, g = l >> 4;
  const int id = blockIdx.x;
  const int bh = (id & 7) + ((id >> 6) << 3);
  const int qbase = ((id >> 3) & 7) * 256;
  const __bf16* Qg = Qb + (size_t)bh * NSEQ * HD;
  const char* Kg = (const char*)(Kb + (size_t)bh * NSEQ * HD);
  const char* Vg = (const char*)(Vtb + (size_t)bh * HD * NSEQ);

  bf16x8 qf[2][4];
#pragma unroll
  for (int qi = 0; qi < 2; ++qi)
#pragma unroll
    for (int s = 0; s < 4; ++s)
      qf[qi][s] = *(const bf16x8*)(Qg + (size_t)(qbase + w * 32 + qi * 16 + a) * HD + s * 32 + g * 8);

  float mrow[2] = {-1e38f, -1e38f}, lrow[2] = {0.f, 0.f};
  f32x4 o[2][8] = {};

  const int ktlo = (qbase >= 1024) ? ((qbase - 1024) >> 6) : 0;
  const int kthi = (qbase + 255) >> 6;

  auto stage = [&](int b, int kt) {
    const int kb2 = kt * 64;
    char* Kl = AL + b * 32768;
    char* Vl = AL + b * 32768 + 16384;
#pragma unroll
    for (int j = 0; j < 2; ++j) {
      const int row = j * 32 + (tid >> 4);
      const int ch = (tid & 15) ^ ((tid >> 4) & 7);
      async16(Kl + j * 8192 + w * 1024, Kg + (size_t)(kb2 + row) * 256 + ch * 16);
    }
#pragma unroll
    for (int j = 0; j < 2; ++j) {
      const int row = j * 64 + (tid >> 3);
      const int ch = (tid & 7) ^ ((tid >> 3) & 7);
      async16(Vl + j * 8192 + w * 1024,
              Vg + (size_t)row * (NSEQ * 2) + (size_t)kb2 * 2 + ch * 16);
    }
  };

  stage(0, ktlo);
  VMCNT0(); BAR();
  int buf = 0;
  char* Pw = AL + 65536 + w * 4096;

  for (int kt = ktlo; kt <= kthi; ++kt) {
    if (kt < kthi) stage(buf ^ 1, kt + 1);
    const char* Kl = AL + buf * 32768;
    const char* Vl = AL + buf * 32768 + 16384;
    const int kb2 = kt * 64;
    const bool full = (kb2 >= qbase + 255 - 1024) && (kb2 + 63 <= qbase);

    f32x4 s4[2][4];
#pragma unroll
    for (int t = 0; t < 4; ++t) {
      bf16x8 kf[4];
#pragma unroll
      for (int ds = 0; ds < 4; ++ds)
        kf[ds] = *(const bf16x8*)(Kl + (t * 16 + a) * 256 + (((ds * 4 + g) ^ (a & 7)) * 16));
      __builtin_amdgcn_s_setprio(1);
#pragma unroll
      for (int qi = 0; qi < 2; ++qi) {
        f32x4 sc = {};
#pragma unroll
        for (int ds = 0; ds < 4; ++ds) sc = mfma16(kf[ds], qf[qi][ds], sc);
        s4[qi][t] = sc;
      }
      __builtin_amdgcn_s_setprio(0);
    }

    if (!full) {
#pragma unroll
      for (int qi = 0; qi < 2; ++qi) {
        const int q = qbase + w * 32 + qi * 16 + a;
#pragma unroll
        for (int t = 0; t < 4; ++t)
#pragma unroll
          for (int i = 0; i < 4; ++i) {
            const int kv = kb2 + t * 16 + g * 4 + i;
            if (kv > q || kv + 1024 < q) s4[qi][t][i] = -1e30f;
          }
      }
    }

#pragma unroll
    for (int qi = 0; qi < 2; ++qi) {
      float pm = s4[qi][0][0];
#pragma unroll
      for (int t = 0; t < 4; ++t)
#pragma unroll
        for (int i = 0; i < 4; ++i)
          if (t || i) pm = fmaxf(pm, s4[qi][t][i]);
      pm = fmaxf(pm, __shfl_xor(pm, 16));
      pm = fmaxf(pm, __shfl_xor(pm, 32));
      if (!__all(pm - mrow[qi] <= 8.f)) {   // T13 defer-max
        const float nm = fmaxf(mrow[qi], pm);
        const float corr = __expf(mrow[qi] - nm);
        mrow[qi] = nm;
        lrow[qi] *= corr;
#pragma unroll
        for (int n = 0; n < 8; ++n)
#pragma unroll
          for (int i = 0; i < 4; ++i) o[qi][n][i] *= corr;
      }
      float rs = 0.f;
#pragma unroll
      for (int t = 0; t < 4; ++t)
#pragma unroll
        for (int i = 0; i < 4; ++i) {
          const float p = __expf(s4[qi][t][i] - mrow[qi]);
          s4[qi][t][i] = p;
          rs += p;
        }
      rs += __shfl_xor(rs, 16);
      rs += __shfl_xor(rs, 32);
      lrow[qi] += rs;
      const int prow = qi * 16 + a;
#pragma unroll
      for (int t = 0; t < 4; ++t) {
        bf16x4 pk = {(__bf16)s4[qi][t][0], (__bf16)s4[qi][t][1],
                     (__bf16)s4[qi][t][2], (__bf16)s4[qi][t][3]};
        const int byte = (prow * 128 + (t * 16 + g * 4) * 2) ^ ((a & 7) << 4);
        *(bf16x4*)(Pw + byte) = pk;
      }
    }

#pragma unroll
    for (int ks = 0; ks < 2; ++ks) {
      bf16x8 pa[2];
#pragma unroll
      for (int qi = 0; qi < 2; ++qi)
        pa[qi] = *(const bf16x8*)(Pw + (((qi * 16 + a) * 128 + ks * 64 + g * 16) ^ ((a & 7) << 4)));
#pragma unroll
      for (int n = 0; n < 8; ++n) {
        bf16x8 va = *(const bf16x8*)(Vl + (n * 16 + a) * 128 + (((ks * 4 + g) ^ (a & 7)) * 16));
        __builtin_amdgcn_s_setprio(1);
#pragma unroll
        for (int qi = 0; qi < 2; ++qi) o[qi][n] = mfma16(va, pa[qi], o[qi][n]);
        __builtin_amdgcn_s_setprio(0);
      }
    }

    VMCNT0(); BAR();
    buf ^= 1;
  }

  const int b_ = bh >> 4, h = bh & 15;
#pragma unroll
  for (int qi = 0; qi < 2; ++qi) {
    const int q = qbase + w * 32 + qi * 16 + a;
    const float inv = 1.f / lrow[qi];
    __bf16* Og = Ob + (size_t)(b_ * NSEQ + q) * DIMC + h * HD + g * 4;
#pragma unroll
    for (int n = 0; n < 8; ++n) {
      bf16x4 pk = {(__bf16)(o[qi][n][0] * inv), (__bf16)(o[qi][n][1] * inv),
                   (__bf16)(o[qi][n][2] * inv), (__bf16)(o[qi][n][3] * inv)};
      *(bf16x4*)(Og + (size_t)n * 16) = pk;
    }
  }
}

// ---------------------------------------------------------------------------
extern "C" void kernel_launch(void* const* d_in, const int* in_sizes, int n_in,
                              void* d_out, int out_size, void* d_ws, size_t ws_size,
                              hipStream_t stream) {
  const float* x = (const float*)d_in[0];
  const float* Wq = (const float*)d_in[1];
  const float* bq = (const float*)d_in[2];
  const float* Wk = (const float*)d_in[3];
  const float* bk = (const float*)d_in[4];
  const float* Wv = (const float*)d_in[5];
  const float* bv = (const float*)d_in[6];
  const float* Wo = (const float*)d_in[7];
  const float* bo = (const float*)d_in[8];
  float* out = (float*)d_out;

  char* ws = (char*)d_ws;
  __bf16* xb    = (__bf16*)(ws + 0);          // 16.78 MB (reused as Ob)
  __bf16* Wqkvb = (__bf16*)(ws + 16777216);   // 25.17 MB
  __bf16* Wob   = (__bf16*)(ws + 41943040);   // 8.39 MB
  __bf16* Qb    = (__bf16*)(ws + 50331648);   // 16.78 MB
  __bf16* Kb    = (__bf16*)(ws + 67108864);   // 16.78 MB
  __bf16* Vtb   = (__bf16*)(ws + 83886080);   // 16.78 MB -> total 100.66 MB
  __bf16* Ob    = xb;

  (void)hipFuncSetAttribute((const void*)attn_swa6,
                            hipFuncAttributeMaxDynamicSharedMemorySize, 98304);

  cast_all<<<dim3((MROWS * DIMC + 4 * DIMC * DIMC) / 1024), 256, 0, stream>>>(
      x, Wq, Wk, Wv, Wo, xb, Wqkvb, Wob);

  gemm_bt<0><<<dim3(NQKV / 128, MROWS / 128), 256, 0, stream>>>(
      xb, Wqkvb, Qb, Kb, Vtb, bq, bk, bv, nullptr);

  attn_swa6<<<dim3(256), 512, 98304, stream>>>(Qb, Kb, Vtb, Ob);

  gemm_bt<1><<<dim3(DIMC / 128, MROWS / 128), 256, 0, stream>>>(
      Ob, Wob, nullptr, nullptr, nullptr, bo, nullptr, nullptr, out);
}